// Round 5
// baseline (199.056 us; speedup 1.0000x reference)
//
#include <hip/hip_runtime.h>
#include <math.h>

#define Bn 32
#define Cn 64
#define Ln 2048
#define NFREQ 1025
#define S0c 341
#define S1c 341
#define S2c 343

#define PI_D 3.14159265358979323846

// padded LDS index: breaks power-of-2 stride bank conflicts
#define PADIX(i) ((i) + ((i) >> 4))

// ---------------- K1: twiddle table tw[t] = e^{-2 pi i t / 2048}, t<2048 ----------------
__global__ void k_twiddle(double2* __restrict__ tw) {
    int t = blockIdx.x * blockDim.x + threadIdx.x;
    if (t < 2048) {
        double ang = -2.0 * PI_D * (double)t / 2048.0;
        double s, c;
        sincos(ang, &s, &c);
        tw[t] = make_double2(c, s);
    }
}

// radix-4 digit reversal of a 10-bit index
__device__ __forceinline__ int rev4_10(unsigned x) {
    unsigned t = __brev(x) >> 22;                       // full 10-bit reversal
    return (int)(((t & 0x155u) << 1) | ((t >> 1) & 0x155u));  // un-reverse bit pairs
}

// ---------------- K2: packed-real rfft via 1024-pt radix-4 complex FFT + split ----------------
__global__ __launch_bounds__(256) void k_fft(const float* __restrict__ X,
                                             const double2* __restrict__ tw,
                                             float* __restrict__ XF) {
    __shared__ double re[1088];
    __shared__ double im[1088];
    int row = blockIdx.x;
    int tid = threadIdx.x;
    const float2* xr = (const float2*)(X + (size_t)row * Ln);
    for (int m = tid; m < 1024; m += 256) {
        float2 v = xr[m];
        re[PADIX(m)] = (double)v.x; im[PADIX(m)] = (double)v.y;  // z[m]=x[2m]+i x[2m+1]
    }
    __syncthreads();
    // 5 radix-4 DIF stages, 256 butterflies each (one per thread)
    #pragma unroll
    for (int s = 0; s < 5; ++s) {
        int log2Q = 8 - 2 * s;
        int Q = 1 << log2Q;
        int k = tid & (Q - 1);
        int g = tid >> log2Q;
        int base = (g << (log2Q + 2)) + k;
        int i0 = PADIX(base), i1 = PADIX(base + Q), i2 = PADIX(base + 2 * Q), i3 = PADIX(base + 3 * Q);
        double ar = re[i0], ai = im[i0];
        double br = re[i1], bi = im[i1];
        double cr = re[i2], ci = im[i2];
        double dr = re[i3], di = im[i3];
        int step = 2 << (2 * s);
        double2 w1 = tw[k * step];
        double2 w2 = tw[2 * k * step];
        double2 w3 = tw[3 * k * step];
        double t0r = ar + cr, t0i = ai + ci;
        double t1r = ar - cr, t1i = ai - ci;
        double t2r = br + dr, t2i = bi + di;
        double t3r = br - dr, t3i = bi - di;
        re[i0] = t0r + t2r; im[i0] = t0i + t2i;
        double u1r = t1r + t3i, u1i = t1i - t3r;
        re[i1] = u1r * w1.x - u1i * w1.y; im[i1] = u1r * w1.y + u1i * w1.x;
        double u2r = t0r - t2r, u2i = t0i - t2i;
        re[i2] = u2r * w2.x - u2i * w2.y; im[i2] = u2r * w2.y + u2i * w2.x;
        double u3r = t1r - t3i, u3i = t1i + t3r;
        re[i3] = u3r * w3.x - u3i * w3.y; im[i3] = u3r * w3.y + u3i * w3.x;
        __syncthreads();
    }
    // split: X[k] = E_k + e^{-2pi i k/2048} O_k from Z (positions radix-4-digit-reversed)
    float* out = XF + (size_t)row * NFREQ;
    for (int k = tid; k <= 1024; k += 256) {
        double Xr, Xi;
        if (k == 0)        { Xr = re[0] + im[0]; Xi = 0.0; }
        else if (k == 1024){ Xr = re[0] - im[0]; Xi = 0.0; }
        else {
            int rv  = PADIX(rev4_10((unsigned)k));
            int rv2 = PADIX(rev4_10((unsigned)(1024 - k)));
            double Zr = re[rv],  Zi = im[rv];
            double Wr = re[rv2], Wi = im[rv2];
            double Er = 0.5 * (Zr + Wr), Ei = 0.5 * (Zi - Wi);
            double Or = 0.5 * (Zi + Wi), Oi = -0.5 * (Zr - Wr);
            double2 t = tw[k];
            Xr = Er + t.x * Or - t.y * Oi;
            Xi = Ei + t.x * Oi + t.y * Or;
        }
        out[k] = (float)sqrt(Xr * Xr + Xi * Xi);
    }
}

// ---------------- K3: fused 3-band GEMM, f32 LDS (lossless cvt at read), f64 acc ----------------
// Tile 32 rows x 64 cols, 4x4 micro, block 128; grid (64, 6, 3) = 1152 blocks.
// LDS traffic halved vs f64 staging: 2x b128 per kk per wave; a-reads 2-way (free).
__global__ __launch_bounds__(128) void k_gemm(const float* __restrict__ XF,
                                              const float* __restrict__ A0,
                                              const float* __restrict__ A1,
                                              const float* __restrict__ A2,
                                              double* __restrict__ Y) {
    const int Sarr[3] = {S0c, S1c, S2c};
    const int Oarr[3] = {0, S0c, S0c + S1c};
    int z = blockIdx.z;
    const float* A = (z == 0) ? A0 : ((z == 1) ? A1 : A2);
    int S = Sarr[z], O = Oarr[z];

    __shared__ alignas(16) float sX[32][36];   // [k][row], 144B rows (16B-aligned)
    __shared__ alignas(16) float sA[32][68];   // [k][col], 272B rows (16B-aligned)
    int r0 = blockIdx.x * 32;
    int d0 = blockIdx.y * 64;
    int tid = threadIdx.x;
    int tx = tid & 15, ty = tid >> 4;   // cols 4tx.., rows 4ty.. (ty 0..7)
    int kl = tid & 31;                  // staging k-local (coalesced global)
    int rl = tid >> 5;                  // staging row/col base (0..3), stride 4

    auto load_tile = [&](int s0, float* px, float* pa) {
        int ss = s0 + kl;
        bool sv = ss < S;
        #pragma unroll
        for (int i = 0; i < 8; ++i)
            px[i] = sv ? XF[(size_t)(r0 + rl + 4 * i) * NFREQ + O + ss] : 0.0f;
        #pragma unroll
        for (int j = 0; j < 16; ++j) {
            int d = d0 + rl + 4 * j;
            pa[j] = (sv && d < S) ? A[(size_t)d * S + ss] : 0.0f;
        }
    };

    double acc[4][4] = {};
    float px[8], pa[16];
    load_tile(0, px, pa);
    int nsteps = (S + 31) / 32;
    for (int st = 0; st < nsteps; ++st) {
        __syncthreads();
        #pragma unroll
        for (int i = 0; i < 8; ++i) sX[kl][rl + 4 * i] = px[i];
        #pragma unroll
        for (int j = 0; j < 16; ++j) sA[kl][rl + 4 * j] = pa[j];
        __syncthreads();
        if (st + 1 < nsteps) load_tile((st + 1) * 32, px, pa);
        #pragma unroll
        for (int kk = 0; kk < 32; ++kk) {
            float4 x4 = *(const float4*)&sX[kk][4 * ty];
            float4 a4 = *(const float4*)&sA[kk][4 * tx];
            double xv[4] = {(double)x4.x, (double)x4.y, (double)x4.z, (double)x4.w};
            double av[4] = {(double)a4.x, (double)a4.y, (double)a4.z, (double)a4.w};
            #pragma unroll
            for (int i = 0; i < 4; ++i)
                #pragma unroll
                for (int j = 0; j < 4; ++j)
                    acc[i][j] = fma(xv[i], av[j], acc[i][j]);
        }
    }
    #pragma unroll
    for (int i = 0; i < 4; ++i) {
        int bc = r0 + 4 * ty + i;
        #pragma unroll
        for (int j = 0; j < 4; ++j) {
            int d = d0 + 4 * tx + j;
            if (d < S) Y[(size_t)bc * NFREQ + O + d] = acc[i][j];
        }
    }
}

// ---------------- K4: weighted Gram partials G = Yw Yw^T per (batch, dim-chunk) ----------------
__global__ __launch_bounds__(256) void k_dist(const double* __restrict__ Y,
                                              const float* __restrict__ fw,
                                              double* __restrict__ part) {
    __shared__ double sY[64][65];
    int b = blockIdx.x;
    int chunk = blockIdx.y;
    int dlo = chunk * 128;
    int dhi = (chunk == 7) ? NFREQ : dlo + 128;
    int tid = threadIdx.x;
    int tx = tid & 15, ty = tid >> 4;

    double f0 = (double)fw[0], f1 = (double)fw[1], f2 = (double)fw[2];
    double m = fmax(f0, fmax(f1, f2));
    double e0 = exp(f0 - m), e1 = exp(f1 - m), e2 = exp(f2 - m);
    double esum = e0 + e1 + e2;
    double sw0 = sqrt(e0 / esum), sw1 = sqrt(e1 / esum), sw2 = sqrt(e2 / esum);

    const double* Yb = Y + (size_t)b * Cn * NFREQ;
    double acc[4][4] = {};
    for (int d0 = dlo; d0 < dhi; d0 += 64) {
        for (int e = tid; e < 64 * 64; e += 256) {
            int r = e >> 6, c = e & 63;
            int d = d0 + c;
            double v = 0.0;
            if (d < dhi) {
                double sw = (d < S0c) ? sw0 : ((d < S0c + S1c) ? sw1 : sw2);
                v = Yb[(size_t)r * NFREQ + d] * sw;
            }
            sY[r][c] = v;
        }
        __syncthreads();
        #pragma unroll 8
        for (int kk = 0; kk < 64; ++kk) {
            double yi[4], yj[4];
            #pragma unroll
            for (int ii = 0; ii < 4; ++ii) yi[ii] = sY[16 * ii + ty][kk];
            #pragma unroll
            for (int jj = 0; jj < 4; ++jj) yj[jj] = sY[16 * jj + tx][kk];
            #pragma unroll
            for (int ii = 0; ii < 4; ++ii)
                #pragma unroll
                for (int jj = 0; jj < 4; ++jj)
                    acc[ii][jj] = fma(yi[ii], yj[jj], acc[ii][jj]);
        }
        __syncthreads();
    }
    double* pb = part + (((size_t)b * 8 + chunk) << 12);
    #pragma unroll
    for (int ii = 0; ii < 4; ++ii)
        #pragma unroll
        for (int jj = 0; jj < 4; ++jj)
            pb[(16 * ii + ty) * 64 + (16 * jj + tx)] = acc[ii][jj];
}

// ---------------- K5: sum Gram partials, dist = Gii+Gjj-2Gij, gumbel decision ----------------
// grid (32 batches, 16 row-groups); block 256 = 4 waves, one wave per matrix row.
__global__ __launch_bounds__(256) void k_decide(const double* __restrict__ part,
                                                const float* __restrict__ gum,
                                                float* __restrict__ out) {
    __shared__ double sQ[64];
    int b = blockIdx.x;
    int tid = threadIdx.x;
    const double* pb = part + (((size_t)b * 8) << 12);
    if (tid < 64) {
        double q = 0.0;
        #pragma unroll
        for (int c = 0; c < 8; ++c) q += pb[((size_t)c << 12) + tid * 65];
        sQ[tid] = q;
    }
    __syncthreads();
    int i = blockIdx.y * 4 + (tid >> 6);
    int j = tid & 63;
    double g = 0.0;
    #pragma unroll
    for (int c = 0; c < 8; ++c) g += pb[((size_t)c << 12) + i * 64 + j];
    double dist = fmax(sQ[i] + sQ[j] - 2.0 * g, 0.0);
    double e = (i == j) ? 0.0 : 1.0 / (dist + 1e-10);
    double emax = e;
    #pragma unroll
    for (int off = 32; off; off >>= 1)
        emax = fmax(emax, __shfl_xor(emax, off, 64));
    double p = (i == j) ? 0.99 : (e / emax) * 0.99;
    double l0 = log(p / (1.0 - p));
    double l1 = log((1.0 - p) / p);
    int idx = i * 64 + j;
    const float* gb = gum + (size_t)b * 8192;
    double y0 = l0 + (double)gb[2 * idx];
    double y1 = l1 + (double)gb[2 * idx + 1];
    out[(size_t)b * 4096 + idx] = (y0 >= y1) ? 1.0f : 0.0f;  // ST == one-hot exactly
}

// ---------------- launcher ----------------
extern "C" void kernel_launch(void* const* d_in, const int* in_sizes, int n_in,
                              void* d_out, int out_size, void* d_ws, size_t ws_size,
                              hipStream_t stream) {
    const float* X  = (const float*)d_in[0];
    const float* A0 = (const float*)d_in[1];
    const float* A1 = (const float*)d_in[2];
    const float* A2 = (const float*)d_in[3];
    const float* fw = (const float*)d_in[4];
    const float* gm = (const float*)d_in[5];
    float* out = (float*)d_out;

    char* ws = (char*)d_ws;
    double2* tw  = (double2*)(ws);                 // 2048*16 = 32,768 B
    float*   XF  = (float*)(ws + 32768);           // 8,396,800 B
    double*  Y   = (double*)(ws + 8429568);        // 16,793,600 B (ends 25,223,168)
    // part aliases XF (dead after gemm): 32*8*4096*8 = 8,388,608 B
    double*  part = (double*)(ws + 32768);

    k_twiddle<<<8, 256, 0, stream>>>(tw);
    k_fft<<<Bn * Cn, 256, 0, stream>>>(X, tw, XF);
    k_gemm<<<dim3(64, 6, 3), 128, 0, stream>>>(XF, A0, A1, A2, Y);
    k_dist<<<dim3(Bn, 8), 256, 0, stream>>>(Y, fw, part);
    k_decide<<<dim3(Bn, 16), 256, 0, stream>>>(part, gm, out);
}

// Round 7
// 184.765 us; speedup vs baseline: 1.0773x; 1.0773x over previous
//
#include <hip/hip_runtime.h>
#include <math.h>

#define Bn 32
#define Cn 64
#define Ln 2048
#define NFREQ 1025
#define S0c 341
#define S1c 341
#define S2c 343

#define PI_D 3.14159265897932  // unused placeholder guard
#undef PI_D
#define PI_D 3.14159265358979323846

typedef double v4d __attribute__((ext_vector_type(4)));

// padded LDS index: breaks power-of-2 stride bank conflicts
#define PADIX(i) ((i) + ((i) >> 4))

// ---------------- K1: twiddle table tw[t] = e^{-2 pi i t / 2048}, t<2048 ----------------
__global__ void k_twiddle(double2* __restrict__ tw) {
    int t = blockIdx.x * blockDim.x + threadIdx.x;
    if (t < 2048) {
        double ang = -2.0 * PI_D * (double)t / 2048.0;
        double s, c;
        sincos(ang, &s, &c);
        tw[t] = make_double2(c, s);
    }
}

// radix-4 digit reversal of a 10-bit index
__device__ __forceinline__ int rev4_10(unsigned x) {
    unsigned t = __brev(x) >> 22;                       // full 10-bit reversal
    return (int)(((t & 0x155u) << 1) | ((t >> 1) & 0x155u));  // un-reverse bit pairs
}

// ---------------- K2: packed-real rfft via 1024-pt radix-4 complex FFT + split ----------------
__global__ __launch_bounds__(256) void k_fft(const float* __restrict__ X,
                                             const double2* __restrict__ tw,
                                             float* __restrict__ XF) {
    __shared__ double re[1088];
    __shared__ double im[1088];
    int row = blockIdx.x;
    int tid = threadIdx.x;
    const float2* xr = (const float2*)(X + (size_t)row * Ln);
    for (int m = tid; m < 1024; m += 256) {
        float2 v = xr[m];
        re[PADIX(m)] = (double)v.x; im[PADIX(m)] = (double)v.y;  // z[m]=x[2m]+i x[2m+1]
    }
    __syncthreads();
    // 5 radix-4 DIF stages, 256 butterflies each (one per thread)
    #pragma unroll
    for (int s = 0; s < 5; ++s) {
        int log2Q = 8 - 2 * s;
        int Q = 1 << log2Q;
        int k = tid & (Q - 1);
        int g = tid >> log2Q;
        int base = (g << (log2Q + 2)) + k;
        int i0 = PADIX(base), i1 = PADIX(base + Q), i2 = PADIX(base + 2 * Q), i3 = PADIX(base + 3 * Q);
        double ar = re[i0], ai = im[i0];
        double br = re[i1], bi = im[i1];
        double cr = re[i2], ci = im[i2];
        double dr = re[i3], di = im[i3];
        int step = 2 << (2 * s);
        double2 w1 = tw[k * step];
        double2 w2 = tw[2 * k * step];
        double2 w3 = tw[3 * k * step];
        double t0r = ar + cr, t0i = ai + ci;
        double t1r = ar - cr, t1i = ai - ci;
        double t2r = br + dr, t2i = bi + di;
        double t3r = br - dr, t3i = bi - di;
        re[i0] = t0r + t2r; im[i0] = t0i + t2i;
        double u1r = t1r + t3i, u1i = t1i - t3r;
        re[i1] = u1r * w1.x - u1i * w1.y; im[i1] = u1r * w1.y + u1i * w1.x;
        double u2r = t0r - t2r, u2i = t0i - t2i;
        re[i2] = u2r * w2.x - u2i * w2.y; im[i2] = u2r * w2.y + u2i * w2.x;
        double u3r = t1r - t3i, u3i = t1i + t3r;
        re[i3] = u3r * w3.x - u3i * w3.y; im[i3] = u3r * w3.y + u3i * w3.x;
        __syncthreads();
    }
    // split: X[k] = E_k + e^{-2pi i k/2048} O_k from Z (positions radix-4-digit-reversed)
    float* out = XF + (size_t)row * NFREQ;
    for (int k = tid; k <= 1024; k += 256) {
        double Xr, Xi;
        if (k == 0)        { Xr = re[0] + im[0]; Xi = 0.0; }
        else if (k == 1024){ Xr = re[0] - im[0]; Xi = 0.0; }
        else {
            int rv  = PADIX(rev4_10((unsigned)k));
            int rv2 = PADIX(rev4_10((unsigned)(1024 - k)));
            double Zr = re[rv],  Zi = im[rv];
            double Wr = re[rv2], Wi = im[rv2];
            double Er = 0.5 * (Zr + Wr), Ei = 0.5 * (Zi - Wi);
            double Or = 0.5 * (Zi + Wi), Oi = -0.5 * (Zr - Wr);
            double2 t = tw[k];
            Xr = Er + t.x * Or - t.y * Oi;
            Xi = Ei + t.x * Oi + t.y * Or;
        }
        out[k] = (float)sqrt(Xr * Xr + Xi * Xi);
    }
}

// ---------------- K3: fused 3-band GEMM via v_mfma_f64_16x16x4, layout-calibrated ----------------
// Tile 64x64, block 256 = 4 waves (2x2), each wave 32x32 = 2x2 MFMAs. f32 LDS staging
// (lossless cvt at frag read), f64 MFMA accumulate. grid (32, 6, 3).
// The C/D register->(row,col) mapping of the f64 MFMA is derived AT RUNTIME with two
// calibration MFMAs (A=lane&15,B=1 and A=1,B=lane&15), making the epilogue correct for
// any (possibly transposed/blocked) hardware layout convention.
__global__ __launch_bounds__(256) void k_gemm(const float* __restrict__ XF,
                                              const float* __restrict__ A0,
                                              const float* __restrict__ A1,
                                              const float* __restrict__ A2,
                                              double* __restrict__ Y) {
    const int Sarr[3] = {S0c, S1c, S2c};
    const int Oarr[3] = {0, S0c, S0c + S1c};
    int z = blockIdx.z;
    const float* A = (z == 0) ? A0 : ((z == 1) ? A1 : A2);
    int S = Sarr[z], O = Oarr[z];

    __shared__ float sX[32][72];   // [k][row], stride 72 words: frag reads 2-way (free)
    __shared__ float sA[32][72];   // [k][col(d)]
    int r0 = blockIdx.x * 64;
    int d0 = blockIdx.y * 64;
    int tid = threadIdx.x;
    int lane = tid & 63, w = tid >> 6;
    int wm = (w >> 1) * 32, wn = (w & 1) * 32;   // wave's 32x32 quadrant
    int fm = lane & 15, kq = lane >> 4;          // staged frag coords (row/col offset, k-quad)
    int kl = tid & 31, rl = tid >> 5;            // staging coords

    // ---- runtime layout calibration ----
    v4d zero = {0.0, 0.0, 0.0, 0.0};
    double aval = (double)fm;
    v4d calR = __builtin_amdgcn_mfma_f64_16x16x4f64(aval, 1.0, zero, 0, 0, 0);
    v4d calC = __builtin_amdgcn_mfma_f64_16x16x4f64(1.0, aval, zero, 0, 0, 0);
    int rIdx[4], cIdx[4];
    #pragma unroll
    for (int i = 0; i < 4; ++i) {
        rIdx[i] = (int)(calR[i] * 0.25);   // staged row offset (0..15) of this reg's element
        cIdx[i] = (int)(calC[i] * 0.25);   // staged col offset (0..15)
    }

    auto load_tile = [&](int s0, float* px, float* pa) {
        int ss = s0 + kl;
        bool sv = ss < S;
        #pragma unroll
        for (int i = 0; i < 8; ++i)
            px[i] = sv ? XF[(size_t)(r0 + rl + 8 * i) * NFREQ + O + ss] : 0.0f;
        #pragma unroll
        for (int j = 0; j < 8; ++j) {
            int d = d0 + rl + 8 * j;
            pa[j] = (sv && d < S) ? A[(size_t)d * S + ss] : 0.0f;
        }
    };

    v4d acc00 = zero, acc01 = zero, acc10 = zero, acc11 = zero;
    float px[8], pa[8];
    load_tile(0, px, pa);
    int nsteps = (S + 31) / 32;   // 11
    for (int st = 0; st < nsteps; ++st) {
        __syncthreads();
        #pragma unroll
        for (int i = 0; i < 8; ++i) sX[kl][rl + 8 * i] = px[i];
        #pragma unroll
        for (int j = 0; j < 8; ++j) sA[kl][rl + 8 * j] = pa[j];
        __syncthreads();
        if (st + 1 < nsteps) load_tile((st + 1) * 32, px, pa);
        #pragma unroll
        for (int t = 0; t < 8; ++t) {
            int k = 4 * t + kq;
            double a0 = (double)sX[k][wm + fm];
            double a1 = (double)sX[k][wm + 16 + fm];
            double b0 = (double)sA[k][wn + fm];
            double b1 = (double)sA[k][wn + 16 + fm];
            acc00 = __builtin_amdgcn_mfma_f64_16x16x4f64(a0, b0, acc00, 0, 0, 0);
            acc01 = __builtin_amdgcn_mfma_f64_16x16x4f64(a0, b1, acc01, 0, 0, 0);
            acc10 = __builtin_amdgcn_mfma_f64_16x16x4f64(a1, b0, acc10, 0, 0, 0);
            acc11 = __builtin_amdgcn_mfma_f64_16x16x4f64(a1, b1, acc11, 0, 0, 0);
        }
    }
    // layout-agnostic store via calibrated indices
    #pragma unroll
    for (int i = 0; i < 4; ++i) {
        int rowA = r0 + wm + rIdx[i];
        int rowB = rowA + 16;
        int dA = d0 + wn + cIdx[i];
        int dB = dA + 16;
        if (dA < S) {
            Y[(size_t)rowA * NFREQ + O + dA] = acc00[i];
            Y[(size_t)rowB * NFREQ + O + dA] = acc10[i];
        }
        if (dB < S) {
            Y[(size_t)rowA * NFREQ + O + dB] = acc01[i];
            Y[(size_t)rowB * NFREQ + O + dB] = acc11[i];
        }
    }
}

// ---------------- K4: weighted Gram partials G = Yw Yw^T per (batch, dim-chunk) ----------------
__global__ __launch_bounds__(256) void k_dist(const double* __restrict__ Y,
                                              const float* __restrict__ fw,
                                              double* __restrict__ part) {
    __shared__ double sY[64][65];
    int b = blockIdx.x;
    int chunk = blockIdx.y;
    int dlo = chunk * 128;
    int dhi = (chunk == 7) ? NFREQ : dlo + 128;
    int tid = threadIdx.x;
    int tx = tid & 15, ty = tid >> 4;

    double f0 = (double)fw[0], f1 = (double)fw[1], f2 = (double)fw[2];
    double m = fmax(f0, fmax(f1, f2));
    double e0 = exp(f0 - m), e1 = exp(f1 - m), e2 = exp(f2 - m);
    double esum = e0 + e1 + e2;
    double sw0 = sqrt(e0 / esum), sw1 = sqrt(e1 / esum), sw2 = sqrt(e2 / esum);

    const double* Yb = Y + (size_t)b * Cn * NFREQ;
    double acc[4][4] = {};
    for (int d0 = dlo; d0 < dhi; d0 += 64) {
        for (int e = tid; e < 64 * 64; e += 256) {
            int r = e >> 6, c = e & 63;
            int d = d0 + c;
            double v = 0.0;
            if (d < dhi) {
                double sw = (d < S0c) ? sw0 : ((d < S0c + S1c) ? sw1 : sw2);
                v = Yb[(size_t)r * NFREQ + d] * sw;
            }
            sY[r][c] = v;
        }
        __syncthreads();
        #pragma unroll 8
        for (int kk = 0; kk < 64; ++kk) {
            double yi[4], yj[4];
            #pragma unroll
            for (int ii = 0; ii < 4; ++ii) yi[ii] = sY[16 * ii + ty][kk];
            #pragma unroll
            for (int jj = 0; jj < 4; ++jj) yj[jj] = sY[16 * jj + tx][kk];
            #pragma unroll
            for (int ii = 0; ii < 4; ++ii)
                #pragma unroll
                for (int jj = 0; jj < 4; ++jj)
                    acc[ii][jj] = fma(yi[ii], yj[jj], acc[ii][jj]);
        }
        __syncthreads();
    }
    double* pb = part + (((size_t)b * 8 + chunk) << 12);
    #pragma unroll
    for (int ii = 0; ii < 4; ++ii)
        #pragma unroll
        for (int jj = 0; jj < 4; ++jj)
            pb[(16 * ii + ty) * 64 + (16 * jj + tx)] = acc[ii][jj];
}

// ---------------- K5: sum Gram partials, dist = Gii+Gjj-2Gij, gumbel decision ----------------
// grid (32 batches, 16 row-groups); block 256 = 4 waves, one wave per matrix row.
__global__ __launch_bounds__(256) void k_decide(const double* __restrict__ part,
                                                const float* __restrict__ gum,
                                                float* __restrict__ out) {
    __shared__ double sQ[64];
    int b = blockIdx.x;
    int tid = threadIdx.x;
    const double* pb = part + (((size_t)b * 8) << 12);
    if (tid < 64) {
        double q = 0.0;
        #pragma unroll
        for (int c = 0; c < 8; ++c) q += pb[((size_t)c << 12) + tid * 65];
        sQ[tid] = q;
    }
    __syncthreads();
    int i = blockIdx.y * 4 + (tid >> 6);
    int j = tid & 63;
    double g = 0.0;
    #pragma unroll
    for (int c = 0; c < 8; ++c) g += pb[((size_t)c << 12) + i * 64 + j];
    double dist = fmax(sQ[i] + sQ[j] - 2.0 * g, 0.0);
    double e = (i == j) ? 0.0 : 1.0 / (dist + 1e-10);
    double emax = e;
    #pragma unroll
    for (int off = 32; off; off >>= 1)
        emax = fmax(emax, __shfl_xor(emax, off, 64));
    double p = (i == j) ? 0.99 : (e / emax) * 0.99;
    double l0 = log(p / (1.0 - p));
    double l1 = log((1.0 - p) / p);
    int idx = i * 64 + j;
    const float* gb = gum + (size_t)b * 8192;
    double y0 = l0 + (double)gb[2 * idx];
    double y1 = l1 + (double)gb[2 * idx + 1];
    out[(size_t)b * 4096 + idx] = (y0 >= y1) ? 1.0f : 0.0f;  // ST == one-hot exactly
}

// ---------------- launcher ----------------
extern "C" void kernel_launch(void* const* d_in, const int* in_sizes, int n_in,
                              void* d_out, int out_size, void* d_ws, size_t ws_size,
                              hipStream_t stream) {
    const float* X  = (const float*)d_in[0];
    const float* A0 = (const float*)d_in[1];
    const float* A1 = (const float*)d_in[2];
    const float* A2 = (const float*)d_in[3];
    const float* fw = (const float*)d_in[4];
    const float* gm = (const float*)d_in[5];
    float* out = (float*)d_out;

    char* ws = (char*)d_ws;
    double2* tw  = (double2*)(ws);                 // 2048*16 = 32,768 B
    float*   XF  = (float*)(ws + 32768);           // 8,396,800 B
    double*  Y   = (double*)(ws + 8429568);        // 16,793,600 B (ends 25,223,168)
    // part aliases XF (dead after gemm): 32*8*4096*8 = 8,388,608 B
    double*  part = (double*)(ws + 32768);

    k_twiddle<<<8, 256, 0, stream>>>(tw);
    k_fft<<<Bn * Cn, 256, 0, stream>>>(X, tw, XF);
    k_gemm<<<dim3(32, 6, 3), 256, 0, stream>>>(XF, A0, A1, A2, Y);
    k_dist<<<dim3(Bn, 8), 256, 0, stream>>>(Y, fw, part);
    k_decide<<<dim3(Bn, 16), 256, 0, stream>>>(part, gm, out);
}

// Round 8
// 169.552 us; speedup vs baseline: 1.1740x; 1.0897x over previous
//
#include <hip/hip_runtime.h>
#include <math.h>

#define Bn 32
#define Cn 64
#define Ln 2048
#define NFREQ 1025
#define S0c 341
#define S1c 341
#define S2c 343

#define PI_D 3.14159265358979323846

typedef double v4d __attribute__((ext_vector_type(4)));

// padded LDS index: breaks power-of-2 stride bank conflicts
#define PADIX(i) ((i) + ((i) >> 4))

// ---------------- K1: twiddle table tw[t] = e^{-2 pi i t / 2048}, t<2048 ----------------
__global__ void k_twiddle(double2* __restrict__ tw) {
    int t = blockIdx.x * blockDim.x + threadIdx.x;
    if (t < 2048) {
        double ang = -2.0 * PI_D * (double)t / 2048.0;
        double s, c;
        sincos(ang, &s, &c);
        tw[t] = make_double2(c, s);
    }
}

// radix-4 digit reversal of a 10-bit index
__device__ __forceinline__ int rev4_10(unsigned x) {
    unsigned t = __brev(x) >> 22;                       // full 10-bit reversal
    return (int)(((t & 0x155u) << 1) | ((t >> 1) & 0x155u));  // un-reverse bit pairs
}

// ---------------- K2: packed-real rfft via 1024-pt radix-4 complex FFT + split ----------------
__global__ __launch_bounds__(256) void k_fft(const float* __restrict__ X,
                                             const double2* __restrict__ tw,
                                             float* __restrict__ XF) {
    __shared__ double re[1088];
    __shared__ double im[1088];
    int row = blockIdx.x;
    int tid = threadIdx.x;
    const float2* xr = (const float2*)(X + (size_t)row * Ln);
    for (int m = tid; m < 1024; m += 256) {
        float2 v = xr[m];
        re[PADIX(m)] = (double)v.x; im[PADIX(m)] = (double)v.y;  // z[m]=x[2m]+i x[2m+1]
    }
    __syncthreads();
    // 5 radix-4 DIF stages, 256 butterflies each (one per thread)
    #pragma unroll
    for (int s = 0; s < 5; ++s) {
        int log2Q = 8 - 2 * s;
        int Q = 1 << log2Q;
        int k = tid & (Q - 1);
        int g = tid >> log2Q;
        int base = (g << (log2Q + 2)) + k;
        int i0 = PADIX(base), i1 = PADIX(base + Q), i2 = PADIX(base + 2 * Q), i3 = PADIX(base + 3 * Q);
        double ar = re[i0], ai = im[i0];
        double br = re[i1], bi = im[i1];
        double cr = re[i2], ci = im[i2];
        double dr = re[i3], di = im[i3];
        int step = 2 << (2 * s);
        double2 w1 = tw[k * step];
        double2 w2 = tw[2 * k * step];
        double2 w3 = tw[3 * k * step];
        double t0r = ar + cr, t0i = ai + ci;
        double t1r = ar - cr, t1i = ai - ci;
        double t2r = br + dr, t2i = bi + di;
        double t3r = br - dr, t3i = bi - di;
        re[i0] = t0r + t2r; im[i0] = t0i + t2i;
        double u1r = t1r + t3i, u1i = t1i - t3r;
        re[i1] = u1r * w1.x - u1i * w1.y; im[i1] = u1r * w1.y + u1i * w1.x;
        double u2r = t0r - t2r, u2i = t0i - t2i;
        re[i2] = u2r * w2.x - u2i * w2.y; im[i2] = u2r * w2.y + u2i * w2.x;
        double u3r = t1r - t3i, u3i = t1i + t3r;
        re[i3] = u3r * w3.x - u3i * w3.y; im[i3] = u3r * w3.y + u3i * w3.x;
        __syncthreads();
    }
    // split: X[k] = E_k + e^{-2pi i k/2048} O_k from Z (positions radix-4-digit-reversed)
    float* out = XF + (size_t)row * NFREQ;
    for (int k = tid; k <= 1024; k += 256) {
        double Xr, Xi;
        if (k == 0)        { Xr = re[0] + im[0]; Xi = 0.0; }
        else if (k == 1024){ Xr = re[0] - im[0]; Xi = 0.0; }
        else {
            int rv  = PADIX(rev4_10((unsigned)k));
            int rv2 = PADIX(rev4_10((unsigned)(1024 - k)));
            double Zr = re[rv],  Zi = im[rv];
            double Wr = re[rv2], Wi = im[rv2];
            double Er = 0.5 * (Zr + Wr), Ei = 0.5 * (Zi - Wi);
            double Or = 0.5 * (Zi + Wi), Oi = -0.5 * (Zr - Wr);
            double2 t = tw[k];
            Xr = Er + t.x * Or - t.y * Oi;
            Xi = Ei + t.x * Oi + t.y * Or;
        }
        out[k] = (float)sqrt(Xr * Xr + Xi * Xi);
    }
}

// ---------------- K3: fused 3-band GEMM via v_mfma_f64_16x16x4, layout-calibrated ----------------
// Tile 64x64, block 256 = 4 waves (2x2), each wave 32x32 = 2x2 MFMAs. Row-major f32 LDS
// stride 34: staging writes AND frag reads are 2-way (free). grid (32, 6, 3).
__global__ __launch_bounds__(256) void k_gemm(const float* __restrict__ XF,
                                              const float* __restrict__ A0,
                                              const float* __restrict__ A1,
                                              const float* __restrict__ A2,
                                              double* __restrict__ Y) {
    const int Sarr[3] = {S0c, S1c, S2c};
    const int Oarr[3] = {0, S0c, S0c + S1c};
    int z = blockIdx.z;
    const float* A = (z == 0) ? A0 : ((z == 1) ? A1 : A2);
    int S = Sarr[z], O = Oarr[z];

    __shared__ float sX[64][34];   // [row][k] stride 34: writes 2-way, reads 2-way (free)
    __shared__ float sA[64][34];   // [col(d)][k]
    int r0 = blockIdx.x * 64;
    int d0 = blockIdx.y * 64;
    int tid = threadIdx.x;
    int lane = tid & 63, w = tid >> 6;
    int wm = (w >> 1) * 32, wn = (w & 1) * 32;   // wave's 32x32 quadrant
    int fm = lane & 15, kq = lane >> 4;          // staged frag coords (row/col offset, k-quad)
    int kl = tid & 31, rl = tid >> 5;            // staging coords

    // ---- runtime layout calibration (proven round 7) ----
    v4d zero = {0.0, 0.0, 0.0, 0.0};
    double aval = (double)fm;
    v4d calR = __builtin_amdgcn_mfma_f64_16x16x4f64(aval, 1.0, zero, 0, 0, 0);
    v4d calC = __builtin_amdgcn_mfma_f64_16x16x4f64(1.0, aval, zero, 0, 0, 0);
    int rIdx[4], cIdx[4];
    #pragma unroll
    for (int i = 0; i < 4; ++i) {
        rIdx[i] = (int)(calR[i] * 0.25);   // staged row offset (0..15) of this reg's element
        cIdx[i] = (int)(calC[i] * 0.25);   // staged col offset (0..15)
    }

    auto load_tile = [&](int s0, float* px, float* pa) {
        int ss = s0 + kl;
        bool sv = ss < S;
        #pragma unroll
        for (int i = 0; i < 8; ++i)
            px[i] = sv ? XF[(size_t)(r0 + rl + 8 * i) * NFREQ + O + ss] : 0.0f;
        #pragma unroll
        for (int j = 0; j < 8; ++j) {
            int d = d0 + rl + 8 * j;
            pa[j] = (sv && d < S) ? A[(size_t)d * S + ss] : 0.0f;
        }
    };

    v4d acc00 = zero, acc01 = zero, acc10 = zero, acc11 = zero;
    float px[8], pa[8];
    load_tile(0, px, pa);
    int nsteps = (S + 31) / 32;   // 11
    for (int st = 0; st < nsteps; ++st) {
        __syncthreads();
        #pragma unroll
        for (int i = 0; i < 8; ++i) sX[rl + 8 * i][kl] = px[i];
        #pragma unroll
        for (int j = 0; j < 8; ++j) sA[rl + 8 * j][kl] = pa[j];
        __syncthreads();
        if (st + 1 < nsteps) load_tile((st + 1) * 32, px, pa);
        #pragma unroll
        for (int t = 0; t < 8; ++t) {
            int k = 4 * t + kq;
            double a0 = (double)sX[wm + fm][k];
            double a1 = (double)sX[wm + 16 + fm][k];
            double b0 = (double)sA[wn + fm][k];
            double b1 = (double)sA[wn + 16 + fm][k];
            acc00 = __builtin_amdgcn_mfma_f64_16x16x4f64(a0, b0, acc00, 0, 0, 0);
            acc01 = __builtin_amdgcn_mfma_f64_16x16x4f64(a0, b1, acc01, 0, 0, 0);
            acc10 = __builtin_amdgcn_mfma_f64_16x16x4f64(a1, b0, acc10, 0, 0, 0);
            acc11 = __builtin_amdgcn_mfma_f64_16x16x4f64(a1, b1, acc11, 0, 0, 0);
        }
    }
    // layout-agnostic store via calibrated indices
    #pragma unroll
    for (int i = 0; i < 4; ++i) {
        int rowA = r0 + wm + rIdx[i];
        int rowB = rowA + 16;
        int dA = d0 + wn + cIdx[i];
        int dB = dA + 16;
        if (dA < S) {
            Y[(size_t)rowA * NFREQ + O + dA] = acc00[i];
            Y[(size_t)rowB * NFREQ + O + dA] = acc10[i];
        }
        if (dB < S) {
            Y[(size_t)rowA * NFREQ + O + dB] = acc01[i];
            Y[(size_t)rowB * NFREQ + O + dB] = acc11[i];
        }
    }
}

// ---------------- K4: weighted Gram partials via f64 MFMA, G = Yw Yw^T ----------------
// grid (32 batches, 8 dim-chunks); block 256 = 4 waves (2x2 quadrants of the 64x64 G).
// One shared f64 LDS tile feeds both A and B fragments (same staging pattern as k_gemm,
// correctness proven by round-7 pass). Pre-scaled by sqrt(w_band) at staging.
__global__ __launch_bounds__(256) void k_dist(const double* __restrict__ Y,
                                              const float* __restrict__ fw,
                                              double* __restrict__ part) {
    __shared__ double sY[64][34];   // [row][k] f64; writes/reads conflict-acceptable
    int b = blockIdx.x;
    int chunk = blockIdx.y;
    int dlo = chunk * 128;
    int dhi = (chunk == 7) ? NFREQ : dlo + 128;
    int tid = threadIdx.x;
    int lane = tid & 63, w = tid >> 6;
    int wm = (w >> 1) * 32, wn = (w & 1) * 32;
    int fm = lane & 15, kq = lane >> 4;
    int kl = tid & 31, rl = tid >> 5;

    double f0 = (double)fw[0], f1 = (double)fw[1], f2 = (double)fw[2];
    double m = fmax(f0, fmax(f1, f2));
    double e0 = exp(f0 - m), e1 = exp(f1 - m), e2 = exp(f2 - m);
    double esum = e0 + e1 + e2;
    double sw0 = sqrt(e0 / esum), sw1 = sqrt(e1 / esum), sw2 = sqrt(e2 / esum);

    v4d zero = {0.0, 0.0, 0.0, 0.0};
    double aval = (double)fm;
    v4d calR = __builtin_amdgcn_mfma_f64_16x16x4f64(aval, 1.0, zero, 0, 0, 0);
    v4d calC = __builtin_amdgcn_mfma_f64_16x16x4f64(1.0, aval, zero, 0, 0, 0);
    int rIdx[4], cIdx[4];
    #pragma unroll
    for (int i = 0; i < 4; ++i) {
        rIdx[i] = (int)(calR[i] * 0.25);
        cIdx[i] = (int)(calC[i] * 0.25);
    }

    const double* Yb = Y + (size_t)b * Cn * NFREQ;
    auto load_tile = [&](int k0, double* py) {
        int d = dlo + k0 + kl;
        bool dv = d < dhi;
        double sw = dv ? ((d < S0c) ? sw0 : ((d < S0c + S1c) ? sw1 : sw2)) : 0.0;
        #pragma unroll
        for (int i = 0; i < 8; ++i)
            py[i] = dv ? Yb[(size_t)(rl + 8 * i) * NFREQ + d] * sw : 0.0;
    };

    v4d acc00 = zero, acc01 = zero, acc10 = zero, acc11 = zero;
    double py[8];
    load_tile(0, py);
    int dk = dhi - dlo;
    int nsteps = (dk + 31) / 32;   // 4 (chunks 0-6) or 5 (chunk 7)
    for (int st = 0; st < nsteps; ++st) {
        __syncthreads();
        #pragma unroll
        for (int i = 0; i < 8; ++i) sY[rl + 8 * i][kl] = py[i];
        __syncthreads();
        if (st + 1 < nsteps) load_tile((st + 1) * 32, py);
        #pragma unroll
        for (int t = 0; t < 8; ++t) {
            int k = 4 * t + kq;
            double a0 = sY[wm + fm][k];
            double a1 = sY[wm + 16 + fm][k];
            double b0 = sY[wn + fm][k];
            double b1 = sY[wn + 16 + fm][k];
            acc00 = __builtin_amdgcn_mfma_f64_16x16x4f64(a0, b0, acc00, 0, 0, 0);
            acc01 = __builtin_amdgcn_mfma_f64_16x16x4f64(a0, b1, acc01, 0, 0, 0);
            acc10 = __builtin_amdgcn_mfma_f64_16x16x4f64(a1, b0, acc10, 0, 0, 0);
            acc11 = __builtin_amdgcn_mfma_f64_16x16x4f64(a1, b1, acc11, 0, 0, 0);
        }
    }
    double* pb = part + (((size_t)b * 8 + chunk) << 12);
    #pragma unroll
    for (int i = 0; i < 4; ++i) {
        int rowA = wm + rIdx[i], rowB = rowA + 16;
        int cA = wn + cIdx[i], cB = cA + 16;
        pb[rowA * 64 + cA] = acc00[i];
        pb[rowA * 64 + cB] = acc01[i];
        pb[rowB * 64 + cA] = acc10[i];
        pb[rowB * 64 + cB] = acc11[i];
    }
}

// ---------------- K5: sum Gram partials, dist = Gii+Gjj-2Gij, gumbel decision ----------------
// grid (32 batches, 16 row-groups); block 256 = 4 waves, one wave per matrix row.
__global__ __launch_bounds__(256) void k_decide(const double* __restrict__ part,
                                                const float* __restrict__ gum,
                                                float* __restrict__ out) {
    __shared__ double sQ[64];
    int b = blockIdx.x;
    int tid = threadIdx.x;
    const double* pb = part + (((size_t)b * 8) << 12);
    if (tid < 64) {
        double q = 0.0;
        #pragma unroll
        for (int c = 0; c < 8; ++c) q += pb[((size_t)c << 12) + tid * 65];
        sQ[tid] = q;
    }
    __syncthreads();
    int i = blockIdx.y * 4 + (tid >> 6);
    int j = tid & 63;
    double g = 0.0;
    #pragma unroll
    for (int c = 0; c < 8; ++c) g += pb[((size_t)c << 12) + i * 64 + j];
    double dist = fmax(sQ[i] + sQ[j] - 2.0 * g, 0.0);
    double e = (i == j) ? 0.0 : 1.0 / (dist + 1e-10);
    double emax = e;
    #pragma unroll
    for (int off = 32; off; off >>= 1)
        emax = fmax(emax, __shfl_xor(emax, off, 64));
    double p = (i == j) ? 0.99 : (e / emax) * 0.99;
    double l0 = log(p / (1.0 - p));
    double l1 = log((1.0 - p) / p);
    int idx = i * 64 + j;
    const float* gb = gum + (size_t)b * 8192;
    double y0 = l0 + (double)gb[2 * idx];
    double y1 = l1 + (double)gb[2 * idx + 1];
    out[(size_t)b * 4096 + idx] = (y0 >= y1) ? 1.0f : 0.0f;  // ST == one-hot exactly
}

// ---------------- launcher ----------------
extern "C" void kernel_launch(void* const* d_in, const int* in_sizes, int n_in,
                              void* d_out, int out_size, void* d_ws, size_t ws_size,
                              hipStream_t stream) {
    const float* X  = (const float*)d_in[0];
    const float* A0 = (const float*)d_in[1];
    const float* A1 = (const float*)d_in[2];
    const float* A2 = (const float*)d_in[3];
    const float* fw = (const float*)d_in[4];
    const float* gm = (const float*)d_in[5];
    float* out = (float*)d_out;

    char* ws = (char*)d_ws;
    double2* tw  = (double2*)(ws);                 // 2048*16 = 32,768 B
    float*   XF  = (float*)(ws + 32768);           // 8,396,800 B
    double*  Y   = (double*)(ws + 8429568);        // 16,793,600 B (ends 25,223,168)
    // part aliases XF (dead after gemm): 32*8*4096*8 = 8,388,608 B
    double*  part = (double*)(ws + 32768);

    k_twiddle<<<8, 256, 0, stream>>>(tw);
    k_fft<<<Bn * Cn, 256, 0, stream>>>(X, tw, XF);
    k_gemm<<<dim3(32, 6, 3), 256, 0, stream>>>(XF, A0, A1, A2, Y);
    k_dist<<<dim3(Bn, 8), 256, 0, stream>>>(Y, fw, part);
    k_decide<<<dim3(Bn, 16), 256, 0, stream>>>(part, gm, out);
}